// Round 2
// 970.931 us; speedup vs baseline: 1.2699x; 1.2699x over previous
//
#include <hip/hip_runtime.h>
#include <hip/hip_bf16.h>

#define B_TOK 65536
#define HDIM  1024
#define EXP   16
#define IDIM  1024

typedef __attribute__((ext_vector_type(8))) short bf16x8_t;   // 8 bf16 (4 VGPRs)
typedef __attribute__((ext_vector_type(4))) float f32x4_t;    // 4 fp32 (native vec)

// ---- helpers ---------------------------------------------------------------

__device__ __forceinline__ unsigned short f2bf(float f) {
    unsigned int u = __float_as_uint(f);
    unsigned int r = (u + 0x7FFFu + ((u >> 16) & 1u)) >> 16;   // RNE
    return (unsigned short)r;
}

__device__ __forceinline__ void async_load16(const void* g, void* l) {
    __builtin_amdgcn_global_load_lds(
        (const __attribute__((address_space(1))) unsigned int*)g,
        (__attribute__((address_space(3))) unsigned int*)l,
        16, 0, 0);
}

// ---- kernel 1: gate (scores + argmax) fused with x f32->bf16 ---------------
// Reduction order kept BIT-IDENTICAL to the round-0 passing kernel (argmax
// tie behavior depends on fp order). Changes: nontemporal x loads via native
// ext_vector f32x4_t (compile fix), zeroes cnts for the parallel scatter.
__global__ __launch_bounds__(256) void gate_kernel(
    const float* __restrict__ x, const float* __restrict__ Wg,
    unsigned short* __restrict__ xbf, int* __restrict__ eidx,
    int* __restrict__ cnts)
{
    __shared__ float wg[EXP * HDIM];          // 64 KB
    const int tid = threadIdx.x;
    if (blockIdx.x == 0 && tid < EXP) cnts[tid] = 0;
    { // cooperative Wg load, coalesced float4
        const f32x4_t* s = (const f32x4_t*)Wg;
        f32x4_t* d = (f32x4_t*)wg;
        for (int i = tid; i < EXP * HDIM / 4; i += 256) d[i] = s[i];
    }
    __syncthreads();

    const int wid = tid >> 6, lane = tid & 63;
    const int gw = blockIdx.x * 4 + wid;      // 4096 waves

    for (int it = 0; it < 4; ++it) {
        const int t0 = gw * 16 + it * 4;
        f32x4_t xv[4][4];
        float acc[4][EXP];
        #pragma unroll
        for (int t = 0; t < 4; ++t) {
            const f32x4_t* row = (const f32x4_t*)(x + (size_t)(t0 + t) * HDIM);
            #pragma unroll
            for (int j = 0; j < 4; ++j)
                xv[t][j] = __builtin_nontemporal_load(row + j * 64 + lane);
        }
        #pragma unroll
        for (int t = 0; t < 4; ++t)
            #pragma unroll
            for (int e = 0; e < EXP; ++e) acc[t][e] = 0.f;

        #pragma unroll
        for (int j = 0; j < 4; ++j) {
            #pragma unroll
            for (int e = 0; e < EXP; ++e) {
                f32x4_t wv = *(const f32x4_t*)(wg + e * HDIM + j * 256 + lane * 4);
                #pragma unroll
                for (int t = 0; t < 4; ++t) {
                    acc[t][e] += xv[t][j][0] * wv[0] + xv[t][j][1] * wv[1]
                               + xv[t][j][2] * wv[2] + xv[t][j][3] * wv[3];
                }
            }
        }
        // bf16 store of x (coalesced: lanes write contiguous 8B)
        #pragma unroll
        for (int t = 0; t < 4; ++t) {
            unsigned short* orow = xbf + (size_t)(t0 + t) * HDIM;
            #pragma unroll
            for (int j = 0; j < 4; ++j) {
                ushort4 o;
                o.x = f2bf(xv[t][j][0]); o.y = f2bf(xv[t][j][1]);
                o.z = f2bf(xv[t][j][2]); o.w = f2bf(xv[t][j][3]);
                *(ushort4*)(orow + j * 256 + lane * 4) = o;
            }
        }
        // reduce + argmax (first-max-wins == np.argmax); in-place on acc
        #pragma unroll
        for (int t = 0; t < 4; ++t) {
            #pragma unroll
            for (int d = 32; d >= 1; d >>= 1) {
                #pragma unroll
                for (int e = 0; e < EXP; ++e)
                    acc[t][e] += __shfl_xor(acc[t][e], d, 64);
            }
            int best = 0; float bv = acc[t][0];
            #pragma unroll
            for (int e = 1; e < EXP; ++e)
                if (acc[t][e] > bv) { bv = acc[t][e]; best = e; }
            if (lane == 0) eidx[t0 + t] = best;
        }
    }
}

// ---- kernel 2: We f32 -> bf16 (nontemporal fp32 loads: read-once) ----------
__global__ __launch_bounds__(256) void convert_we(
    const float* __restrict__ we, unsigned short* __restrict__ webf)
{
    const size_t n4 = (size_t)EXP * IDIM * HDIM / 4;
    const size_t stride = (size_t)gridDim.x * 256;
    for (size_t i = (size_t)blockIdx.x * 256 + threadIdx.x; i < n4; i += stride) {
        f32x4_t v = __builtin_nontemporal_load((const f32x4_t*)we + i);
        ushort4 o;
        o.x = f2bf(v[0]); o.y = f2bf(v[1]); o.z = f2bf(v[2]); o.w = f2bf(v[3]);
        ((ushort4*)webf)[i] = o;
    }
}

// ---- kernel 3: parallel token-list build ------------------------------------
// 1024 waves, one token/thread. Per-wave ballot aggregation -> one atomicAdd
// per (wave, expert). Order within an expert's list is irrelevant (each token's
// output row is computed identically wherever it lands).
__global__ __launch_bounds__(256) void scatter_kernel(
    const int* __restrict__ eidx, int* __restrict__ token_list,
    int* __restrict__ counts)
{
    const int b = blockIdx.x * 256 + threadIdx.x;
    const int lane = threadIdx.x & 63;
    const int e = eidx[b];
    unsigned long long mymask = 0;
    int baseval = 0;
    #pragma unroll
    for (int ex = 0; ex < EXP; ++ex) {
        unsigned long long m = __ballot(e == ex);
        if (e == ex) mymask = m;
        int c = __popcll(m);
        if (lane == ex && c) baseval = atomicAdd(&counts[ex], c);
    }
    const int base = __shfl(baseval, e, 64);
    const int pos = base + __popcll(mymask & ((1ull << lane) - 1ull));
    token_list[(size_t)e * B_TOK + pos] = b;
}

// ---- kernel 4: grouped GEMM -------------------------------------------------
//  (a) T2 both-sides XOR swizzle: global source segment pre-swizzled
//      (kseg ^ (rgrp&7)), LDS dest linear (global_load_lds requirement),
//      read address applies the same XOR -> 2-way (free) instead of 16-phase.
//  (b) T3-minimal double-buffer: stage tile t+1 before computing tile t,
//      one __syncthreads() per K-step (its vmcnt drain is the wait).
//  (c) m-fastest + XCD chunking: each XCD owns 2 experts; consecutive m-tiles
//      per (e,n) share a 256-KB B-slice in its L2.
//  (d) nontemporal epilogue stores (out is write-once; keep L3 for xbf/webf).
__global__ __launch_bounds__(256) void moe_gemm(
    const unsigned short* __restrict__ xbf,
    const unsigned short* __restrict__ webf,
    const int* __restrict__ token_list,
    const int* __restrict__ counts,
    float* __restrict__ out)
{
    // linear id in dispatch order (x fastest), then XCD-chunked remap
    const int lin = blockIdx.x + 512 * (blockIdx.y + 8 * blockIdx.z);
    const int logical = (lin & 7) * 8192 + (lin >> 3);   // 65536 % 8 == 0: bijective
    const int mt = logical & 511;          // m-tile: fastest within a chunk
    const int nt = (logical >> 9) & 7;
    const int e  = logical >> 12;

    const int cnt = counts[e];
    const int m0 = mt * 128;
    if (m0 >= cnt) return;
    const int row_count = min(128, cnt - m0);
    const int n0 = nt * 128;

    __shared__ unsigned short As0[128 * 64];   // 16 KB each; 64 KB total
    __shared__ unsigned short Bs0[128 * 64];
    __shared__ unsigned short As1[128 * 64];
    __shared__ unsigned short Bs1[128 * 64];

    const int tid = threadIdx.x;
    const int wid = tid >> 6, lane = tid & 63;
    const int rgrp = tid >> 3;                // 0..31: row within 32-row chunk
    const int kseg = tid & 7;                 // 16B segment within 128B row
    const int ksw  = kseg ^ (rgrp & 7);       // swizzled SOURCE segment

    const int* tl = token_list + (size_t)e * B_TOK + m0;
    size_t abase[4], bbase[4];
    #pragma unroll
    for (int i = 0; i < 4; ++i) {
        const int r = i * 32 + rgrp;
        const int tok = tl[min(r, row_count - 1)];
        abase[i] = ((size_t)tok * HDIM + ksw * 8) * 2;
        bbase[i] = (((size_t)e * IDIM + n0 + r) * HDIM + ksw * 8) * 2;
    }
    const char* xg = (const char*)xbf;
    const char* wp = (const char*)webf;

    f32x4_t acc[4][4];
    const f32x4_t z = {0.f, 0.f, 0.f, 0.f};
    #pragma unroll
    for (int mi = 0; mi < 4; ++mi)
        #pragma unroll
        for (int ni = 0; ni < 4; ++ni) acc[mi][ni] = z;

    const int wm = wid >> 1, wn = wid & 1;
    const int quad = lane >> 4, l16 = lane & 15;
    const int rx = l16 & 7;                       // row&7 for all our rows
    const int s0 = (quad ^ rx) << 3;              // swizzled read seg, kk=0
    const int s1 = ((quad + 4) ^ rx) << 3;        // swizzled read seg, kk=32
    const int arow0 = (wm * 64 + l16) * 64;       // shorts
    const int brow0 = (wn * 64 + l16) * 64;

#define STAGE(AP, BP, K0)                                                      \
    { _Pragma("unroll")                                                        \
      for (int i = 0; i < 4; ++i) {                                            \
        async_load16(xg + abase[i] + (size_t)(K0) * 2,                         \
                     (char*)(AP) + i * 4096 + tid * 16);                       \
        async_load16(wp + bbase[i] + (size_t)(K0) * 2,                         \
                     (char*)(BP) + i * 4096 + tid * 16);                       \
      } }

#define COMPUTE(AP, BP)                                                        \
    { _Pragma("unroll")                                                        \
      for (int kkh = 0; kkh < 2; ++kkh) {                                      \
        const int co = kkh ? s1 : s0;                                          \
        bf16x8_t av[4], bv[4];                                                 \
        _Pragma("unroll")                                                      \
        for (int mi = 0; mi < 4; ++mi)                                         \
            av[mi] = *(const bf16x8_t*)((AP) + arow0 + mi * 1024 + co);        \
        _Pragma("unroll")                                                      \
        for (int ni = 0; ni < 4; ++ni)                                         \
            bv[ni] = *(const bf16x8_t*)((BP) + brow0 + ni * 1024 + co);        \
        _Pragma("unroll")                                                      \
        for (int mi = 0; mi < 4; ++mi)                                         \
            _Pragma("unroll")                                                  \
            for (int ni = 0; ni < 4; ++ni)                                     \
                acc[mi][ni] = __builtin_amdgcn_mfma_f32_16x16x32_bf16(         \
                    av[mi], bv[ni], acc[mi][ni], 0, 0, 0);                     \
      } }

    STAGE(As0, Bs0, 0);
    __syncthreads();                              // drains the prologue stage

    for (int t = 0; t < 16; t += 2) {
        STAGE(As1, Bs1, (t + 1) * 64);            // issue next tile first
        COMPUTE(As0, Bs0);                        // loads fly under compute
        __syncthreads();                          // vmcnt(0)+lgkmcnt(0)+barrier
        if (t + 2 < 16) STAGE(As0, Bs0, (t + 2) * 64);
        COMPUTE(As1, Bs1);
        __syncthreads();
    }

    // epilogue: C/D layout col = lane&15, row = (lane>>4)*4 + reg
    #pragma unroll
    for (int mi = 0; mi < 4; ++mi) {
        const int rl0 = wm * 64 + mi * 16 + quad * 4;
        #pragma unroll
        for (int r = 0; r < 4; ++r) {
            const int rl = rl0 + r;
            if (rl < row_count) {
                const int tok = tl[rl];
                float* orow = out + (size_t)tok * IDIM + n0 + wn * 64 + l16;
                #pragma unroll
                for (int ni = 0; ni < 4; ++ni)
                    __builtin_nontemporal_store(acc[mi][ni][r], orow + ni * 16);
            }
        }
    }
#undef STAGE
#undef COMPUTE
}

// ---- launcher --------------------------------------------------------------
extern "C" void kernel_launch(void* const* d_in, const int* in_sizes, int n_in,
                              void* d_out, int out_size, void* d_ws, size_t ws_size,
                              hipStream_t stream) {
    const float* x  = (const float*)d_in[0];
    const float* Wg = (const float*)d_in[1];
    const float* We = (const float*)d_in[2];
    float* out = (float*)d_out;

    char* ws = (char*)d_ws;
    // ws layout (bytes):
    //   [0, 128 MiB)        x_bf16   [65536][1024]
    //   [+,  32 MiB)        we_bf16  [16][1024][1024]
    //   [+, 256 KiB)        eidx     [65536] int
    //   [+, 256 B  )        counts   [16] int
    //   [+,   4 MiB)        token_list [16][65536] int
    unsigned short* xbf   = (unsigned short*)(ws);
    unsigned short* webf  = (unsigned short*)(ws + 134217728);
    int*            eidx  = (int*)(ws + 167772160);
    int*            cnts  = (int*)(ws + 168034304);
    int*            tlist = (int*)(ws + 168034560);

    gate_kernel<<<1024, 256, 0, stream>>>(x, Wg, xbf, eidx, cnts);
    convert_we<<<4096, 256, 0, stream>>>(We, webf);
    scatter_kernel<<<256, 256, 0, stream>>>(eidx, tlist, cnts);
    moe_gemm<<<dim3(512, 8, 16), 256, 0, stream>>>(xbf, webf, tlist, cnts, out);
}